// Round 3
// baseline (796.798 us; speedup 1.0000x reference)
//
#include <hip/hip_runtime.h>
#include <hip/hip_bf16.h>

// Problem constants
#define BATCH 32
#define NSEQ  16384
#define DDIM  65
#define CHUNK 64
#define KQ    64
#define NBLK  256          // NSEQ / CHUNK
#define SCALE 0.12403473458920847f   // 65^-0.5
#define TCH   4            // chunks per block (k_attn)
#define GRP   64           // NBLK / TCH  -> partial groups per batch

typedef __bf16 bf16x8 __attribute__((ext_vector_type(8)));
typedef __bf16 bf16x4 __attribute__((ext_vector_type(4)));
typedef float  f32x4  __attribute__((ext_vector_type(4)));
#define MFMA16(a, b, c) __builtin_amdgcn_mfma_f32_16x16x32_bf16(a, b, c, 0, 0, 0)

__device__ __forceinline__ float gelu_exact(float v) {
    return 0.5f * v * (1.0f + erff(v * 0.7071067811865476f));
}

// tanh-approx GELU in sigmoid form: gelu = x * sigmoid(2t),
// 2t = 1.5957691x(1+0.044715x^2).  |err| <= ~2e-4 (same poly as before).
__device__ __forceinline__ float gelu_tanh(float x) {
    float x2 = x * x;
    float z  = x * fmaf(-0.07135481627f, x2, -1.59576912161f);  // -2t
    float e  = __expf(z);
    return x * __builtin_amdgcn_rcpf(e + 1.0f);
}

// ---------------------------------------------------------------------------
// Kernel 0: prep tables (unchanged from round 2).
// ---------------------------------------------------------------------------
__global__ __launch_bounds__(256) void k_prep(const float* __restrict__ Wk,
                                              const float* __restrict__ Wv,
                                              const float* __restrict__ pos,
                                              __bf16* __restrict__ WkT,
                                              __bf16* __restrict__ WvT,
                                              float* __restrict__ posK,
                                              float* __restrict__ posV,
                                              float* __restrict__ wkc,
                                              float* __restrict__ wvc) {
    int i = blockIdx.x * 256 + threadIdx.x;
    if (i < 10240) {
        int m = i / 5120;
        int j = i - m * 5120;
        int d = j >> 6, e = j & 63;
        const float* W = m ? Wv : Wk;
        __bf16* T = m ? WvT : WkT;
        T[(size_t)d * 64 + e] = (d < DDIM) ? (__bf16)W[e * DDIM + d] : (__bf16)0.0f;
    } else if (i < 14592) {
        int j = i - 10240;
        int c = j / 68, d = j - c * 68;
        posK[j] = (d < DDIM) ? pos[c * DDIM + d] : 0.f;
    } else if (i < 19012) {
        int j = i - 14592;
        int d = j / 68, c = j - d * 68;
        posV[j] = (d < DDIM && c < 64) ? pos[c * DDIM + d] : 0.f;
    } else if (i < 19080) {
        int d = i - 19012;
        wkc[d] = (d < DDIM) ? Wk[64 * DDIM + d] : 0.f;
    } else if (i < 19148) {
        int d = i - 19080;
        wvc[d] = (d < DDIM) ? Wv[64 * DDIM + d] : 0.f;
    }
}

// ---------------------------------------------------------------------------
// Kernel 1: per-slice partial sums over N (unchanged).  grid (64, 32).
// ---------------------------------------------------------------------------
__global__ __launch_bounds__(256) void k_gavg(const float* __restrict__ x,
                                              float* __restrict__ partial) {
    const int s = blockIdx.x;
    const int b = blockIdx.y;
    const int tid = threadIdx.x;
    const int w = tid >> 6, lane = tid & 63;
    const float* xb = x + (size_t)b * NSEQ * DDIM;
    const int n0 = s * 256;
    float acc = 0.f, acce = 0.f;
    #pragma unroll 4
    for (int i = 0; i < 64; ++i) {
        const float* row = xb + (size_t)(n0 + w + i * 4) * DDIM;
        acc  += row[lane];
        acce += row[64];
    }
    __shared__ float part[4][DDIM];
    part[w][lane] = acc;
    if (lane == 0) part[w][64] = acce;
    __syncthreads();
    if (tid < DDIM) {
        partial[((size_t)b * 64 + s) * DDIM + tid] =
            part[0][tid] + part[1][tid] + part[2][tid] + part[3][tid];
    }
}

// ---------------------------------------------------------------------------
// Kernel 2a: reduce partials -> gavg; h = gelu(gavg@Wq1+bq1); r = gavg@Wr+br.
// ---------------------------------------------------------------------------
__global__ __launch_bounds__(256) void k_qgen1(const float* __restrict__ partial,
    const float* __restrict__ Wq1, const float* __restrict__ bq1,
    const float* __restrict__ Wr,  const float* __restrict__ br,
    float* __restrict__ h_out, float* __restrict__ r_out) {
    const int b = blockIdx.x, tid = threadIdx.x;
    __shared__ float g[DDIM];
    if (tid < DDIM) {
        float a = 0.f;
        const float* p = partial + (size_t)b * 64 * DDIM + tid;
        #pragma unroll 8
        for (int s = 0; s < 64; ++s) a += p[s * DDIM];
        g[tid] = a * (1.0f / 16384.0f);
    }
    __syncthreads();
    if (tid < DDIM) {
        float a = bq1[tid];
        for (int e = 0; e < DDIM; ++e) a += g[e] * Wq1[e * DDIM + tid];
        h_out[b * DDIM + tid] = gelu_exact(a);
    } else if (tid >= 128 && tid < 128 + DDIM) {
        const int d = tid - 128;
        float a = br[d];
        for (int e = 0; e < DDIM; ++e) a += g[e] * Wr[e * DDIM + d];
        r_out[b * DDIM + d] = a;
    }
}

// ---------------------------------------------------------------------------
// Kernel 2b: q = (h@Wq2+bq2)*SCALE -> qbf [64][64] bf16 + q64 col (unchanged).
// ---------------------------------------------------------------------------
__global__ __launch_bounds__(256) void k_qgen2(const float* __restrict__ h_in,
    const float* __restrict__ Wq2, const float* __restrict__ bq2,
    __bf16* __restrict__ qbf, float* __restrict__ q64) {
    const int b = blockIdx.y, tid = threadIdx.x;
    const int o = blockIdx.x * 256 + tid;
    __shared__ float h[DDIM];
    if (tid < DDIM) h[tid] = h_in[b * DDIM + tid];
    __syncthreads();
    if (o >= KQ * DDIM) return;
    float a = bq2[o];
    #pragma unroll 13
    for (int e = 0; e < DDIM; ++e) a += h[e] * Wq2[e * (KQ * DDIM) + o];
    a *= SCALE;
    const int k = o / DDIM, d = o - k * DDIM;
    if (d < 64) qbf[(size_t)b * 4096 + k * 64 + d] = (__bf16)a;
    else        q64[b * 64 + k] = a;
}

// ---------------------------------------------------------------------------
// Kernel 3 (MFMA): grid (GRP=64, BATCH).  Each block owns TCH=4 consecutive
// chunks and keeps an online cross-softmax state (m, s, O[65]) per k in
// registers -- blk/cs are never materialized.  Next chunk's x is loaded into
// registers right after BAR_B and staged to LDS after ph4 (latency hidden
// under QK/softmax/PV).  Writes one 68-f32 partial per (b,k,g).
// ---------------------------------------------------------------------------
__global__ __launch_bounds__(256, 4) void k_attn(
    const float* __restrict__ x,
    const __bf16* __restrict__ qbf, const float* __restrict__ q64g,
    const __bf16* __restrict__ WkT, const __bf16* __restrict__ WvT,
    const float* __restrict__ posK, const float* __restrict__ posV,
    const float* __restrict__ wkc, const float* __restrict__ wvc,
    const float* __restrict__ bkb, const float* __restrict__ bvb,
    const float* __restrict__ cq,
    float* __restrict__ part) {
    const int g  = blockIdx.x;
    const int b  = blockIdx.y;
    const int nb0 = g * TCH;
    const int tid = threadIdx.x;
    const int lane = tid & 63, w = tid >> 6;
    const int l16 = lane & 15, quad = lane >> 4;

    __shared__ __align__(16) __bf16 xP[64 * 64];     // x chunk, then P (swizzled)
    __shared__ __align__(16) __bf16 keysL[64 * 64];  // [c][d0..63] swizzled
    __shared__ __align__(16) __bf16 valsT[64 * 64];  // [d][c0..63] swizzled
    __shared__ __align__(16) __bf16 kcol64[64];      // keys[c][64]
    __shared__ __align__(16) __bf16 vcol64[64];      // vals[c][64]
    __shared__ float xs64[64];                       // x[c][64] fp32

    // hoisted q fragments (loop-invariant)
    const int krow = w * 16 + l16;                   // this lane's k
    const __bf16* qr = qbf + (size_t)b * 4096 + krow * 64 + quad * 8;
    bf16x8 q0 = *(const bf16x8*)qr;
    bf16x8 q1 = *(const bf16x8*)(qr + 32);
    const float q64k = q64g[b * 64 + krow];
    const float cq64 = cq[64];

    // online cross-softmax state (per lane: k = krow, d = mt*16+quad*4+r)
    f32x4 O[4];
    #pragma unroll
    for (int mt = 0; mt < 4; ++mt) O[mt] = f32x4{0.f, 0.f, 0.f, 0.f};
    float O64 = 0.f, mrun = -1e30f, srun = 0.f;

    // staging mapping: thread -> (row cst, quarter gst); own-wave rows.
    const int cst = tid >> 2, gst = tid & 3;
    const int swst = (cst & 7) << 4;

    // prefetch chunk 0 into registers
    float xr[16], xen;
    {
        const float* xrow = x + ((size_t)b * NSEQ + (size_t)nb0 * CHUNK + cst) * DDIM;
        #pragma unroll
        for (int j = 0; j < 16; ++j) xr[j] = xrow[gst + 4 * j];
        xen = (gst == 0) ? xrow[64] : 0.f;
    }

    for (int t = 0; t < TCH; ++t) {
        // ---- stage regs -> swizzled xP (own-wave rows; no barrier needed) ----
        {
            char* dst = (char*)xP + cst * 128;
            #pragma unroll
            for (int j = 0; j < 16; ++j) {
                const int e = gst + 4 * j;
                *(__bf16*)(dst + ((((e >> 3) << 4) ^ swst) + (e & 7) * 2)) = (__bf16)xr[j];
            }
            if (gst == 0) xs64[cst] = xen;
        }
        __syncthreads();   // BAR_A: keysL/valsT free (prev iter readers done)

        // ---- ph2: keys/vals via MFMA + gelu, written pre-transposed ----
        {
            const int crow = w * 16 + l16;
            const int sw_c = (crow & 7) << 4;
            const char* xrow = (const char*)xP + crow * 128;
            bf16x8 x0 = *(const bf16x8*)(xrow + ((quad * 16) ^ sw_c));
            bf16x8 x1 = *(const bf16x8*)(xrow + ((quad * 16 + 64) ^ sw_c));
            const float xe_c = xs64[crow];
            const f32x4 z = {0.f, 0.f, 0.f, 0.f};

            f32x4 kacc[5];
            #pragma unroll
            for (int mt = 0; mt < 5; ++mt) {
                const __bf16* wr = WkT + (mt * 16 + l16) * 64 + quad * 8;
                kacc[mt] = MFMA16(*(const bf16x8*)wr, x0, z);
                kacc[mt] = MFMA16(*(const bf16x8*)(wr + 32), x1, kacc[mt]);
            }
            #pragma unroll
            for (int mt = 0; mt < 4; ++mt) {
                const int d0 = mt * 16 + quad * 4;
                const f32x4 pk  = *(const f32x4*)(posK + crow * 68 + d0);
                const f32x4 wk4 = *(const f32x4*)(wkc + d0);
                const f32x4 bk4 = *(const f32x4*)(bkb + d0);
                bf16x4 kv;
                #pragma unroll
                for (int r = 0; r < 4; ++r) {
                    const float pre = kacc[mt][r] + xe_c * wk4[r] + bk4[r];
                    kv[r] = (__bf16)(gelu_tanh(pre) + pk[r]);
                }
                *(bf16x4*)((char*)keysL + crow * 128 + ((d0 * 2) ^ sw_c)) = kv;
            }
            if (quad == 0) {  // d = 64
                const float pre = kacc[4][0] + xe_c * wkc[64] + bkb[64];
                kcol64[crow] = (__bf16)(gelu_tanh(pre) + posK[crow * 68 + 64]);
            }

            f32x4 vacc[5];
            #pragma unroll
            for (int nt = 0; nt < 5; ++nt) {
                const __bf16* wr = WvT + (nt * 16 + l16) * 64 + quad * 8;
                vacc[nt] = MFMA16(x0, *(const bf16x8*)wr, z);
                vacc[nt] = MFMA16(x1, *(const bf16x8*)(wr + 32), vacc[nt]);
            }
            const int cv0 = w * 16 + quad * 4;
            float xe4[4];
            #pragma unroll
            for (int r = 0; r < 4; ++r) xe4[r] = xs64[cv0 + r];
            #pragma unroll
            for (int nt = 0; nt < 4; ++nt) {
                const int d = nt * 16 + l16;
                const float wvd = wvc[d], bvd = bvb[d];
                const f32x4 pv = *(const f32x4*)(posV + d * 68 + cv0);
                bf16x4 vv;
                #pragma unroll
                for (int r = 0; r < 4; ++r) {
                    const float pre = vacc[nt][r] + xe4[r] * wvd + bvd;
                    vv[r] = (__bf16)(gelu_tanh(pre) + pv[r]);
                }
                *(bf16x4*)((char*)valsT + d * 128 + ((cv0 * 2) ^ ((d & 7) << 4))) = vv;
            }
            if (l16 == 0) {  // d = 64
                const float wvd = wvc[64], bvd = bvb[64];
                const f32x4 pv = *(const f32x4*)(posV + 64 * 68 + cv0);
                bf16x4 vv;
                #pragma unroll
                for (int r = 0; r < 4; ++r) {
                    const float pre = vacc[4][r] + xe4[r] * wvd + bvd;
                    vv[r] = (__bf16)(gelu_tanh(pre) + pv[r]);
                }
                *(bf16x4*)((char*)vcol64 + cv0 * 2) = vv;
            }
        }
        __syncthreads();   // BAR_B

        // ---- issue next chunk's x loads (latency hides under ph3/ph4) ----
        if (t + 1 < TCH) {
            const float* xrow =
                x + ((size_t)b * NSEQ + (size_t)(nb0 + t + 1) * CHUNK + cst) * DDIM;
            #pragma unroll
            for (int j = 0; j < 16; ++j) xr[j] = xrow[gst + 4 * j];
            xen = (gst == 0) ? xrow[64] : 0.f;
        }

        // ---- ph3: S^T, lane-local softmax over c, P store, d=64 column ----
        float inv_k, o64n;
        {
            const f32x4 z = {0.f, 0.f, 0.f, 0.f};
            float st[4][4];
            #pragma unroll
            for (int mt = 0; mt < 4; ++mt) {
                const int cA = mt * 16 + l16;
                const char* kr = (const char*)keysL + cA * 128;
                const int swc = (cA & 7) << 4;
                f32x4 s = MFMA16(*(const bf16x8*)(kr + ((quad * 16) ^ swc)), q0, z);
                s = MFMA16(*(const bf16x8*)(kr + ((quad * 16 + 64) ^ swc)), q1, s);
                bf16x4 k4 = *(const bf16x4*)((const char*)kcol64 + (mt * 16 + quad * 4) * 2);
                #pragma unroll
                for (int r = 0; r < 4; ++r)
                    st[mt][r] = fmaf(q64k, (float)k4[r], s[r]) * SCALE;
            }
            float m = st[0][0];
            #pragma unroll
            for (int mt = 0; mt < 4; ++mt)
                #pragma unroll
                for (int r = 0; r < 4; ++r) m = fmaxf(m, st[mt][r]);
            m = fmaxf(m, __shfl_xor(m, 16));
            m = fmaxf(m, __shfl_xor(m, 32));
            float sum = 0.f;
            #pragma unroll
            for (int mt = 0; mt < 4; ++mt)
                #pragma unroll
                for (int r = 0; r < 4; ++r) {
                    st[mt][r] = __expf(st[mt][r] - m);
                    sum += st[mt][r];
                }
            sum += __shfl_xor(sum, 16);
            sum += __shfl_xor(sum, 32);
            inv_k = __builtin_amdgcn_rcpf(sum);

            // store unnormalized P into own k-row of xP (swizzled)
            const int swk = (krow & 7) << 4;
            char* prow = (char*)xP + krow * 128;
            #pragma unroll
            for (int mt = 0; mt < 4; ++mt) {
                bf16x4 p4;
                #pragma unroll
                for (int r = 0; r < 4; ++r) p4[r] = (__bf16)st[mt][r];
                *(bf16x4*)(prow + (((mt * 16 + quad * 4) * 2) ^ swk)) = p4;
            }

            // d=64 output column from fp32 P
            float o = 0.f;
            #pragma unroll
            for (int mt = 0; mt < 4; ++mt) {
                bf16x4 v4 = *(const bf16x4*)((const char*)vcol64 + (mt * 16 + quad * 4) * 2);
                #pragma unroll
                for (int r = 0; r < 4; ++r) o = fmaf(st[mt][r], (float)v4[r], o);
            }
            o += __shfl_xor(o, 16);
            o += __shfl_xor(o, 32);
            o64n = o * inv_k;
        }

        // ---- ph4: blk^T = valsT@P (kept in regs) + cs, then online update ----
        {
            const f32x4 z = {0.f, 0.f, 0.f, 0.f};
            const int swk = (krow & 7) << 4;
            const char* prow = (const char*)xP + krow * 128;
            bf16x8 p0 = *(const bf16x8*)(prow + ((quad * 16) ^ swk));
            bf16x8 p1 = *(const bf16x8*)(prow + ((quad * 16 + 64) ^ swk));
            f32x4 oo[4];
            float csp = 0.f;
            #pragma unroll
            for (int mt = 0; mt < 4; ++mt) {
                const int dA = mt * 16 + l16;
                const char* vr = (const char*)valsT + dA * 128;
                const int swd = (dA & 7) << 4;
                f32x4 o = MFMA16(*(const bf16x8*)(vr + ((quad * 16) ^ swd)), p0, z);
                o = MFMA16(*(const bf16x8*)(vr + ((quad * 16 + 64) ^ swd)), p1, o);
                oo[mt] = o;
                const int d0 = mt * 16 + quad * 4;
                const f32x4 cq4 = *(const f32x4*)(cq + d0);
                #pragma unroll
                for (int r = 0; r < 4; ++r) csp = fmaf(o[r], cq4[r], csp);
            }
            csp += __shfl_xor(csp, 16);
            csp += __shfl_xor(csp, 32);
            const float cs = (csp * inv_k + cq64 * o64n) * SCALE;

            // online cross-softmax accumulate
            const float mn = fmaxf(mrun, cs);
            const float a  = __expf(mrun - mn);
            const float e  = __expf(cs - mn);
            srun = srun * a + e;
            const float ei = e * inv_k;
            #pragma unroll
            for (int mt = 0; mt < 4; ++mt)
                #pragma unroll
                for (int r = 0; r < 4; ++r)
                    O[mt][r] = O[mt][r] * a + oo[mt][r] * ei;
            O64 = O64 * a + o64n * e;
            mrun = mn;
        }
    }

    // ---- store partial: part[b][k][g][68] = {O[0..64], m, s, pad} ----
    {
        float* dst = part + (((size_t)(b * 64 + krow)) * GRP + g) * 68;
        #pragma unroll
        for (int mt = 0; mt < 4; ++mt)
            *(f32x4*)(dst + mt * 16 + quad * 4) = O[mt];
        if (quad == 0) {
            f32x4 tail = {O64, mrun, srun, 0.f};
            *(f32x4*)(dst + 64) = tail;
        }
    }
}

// ---------------------------------------------------------------------------
// Kernel 4: merge GRP partials per (b,k): global softmax renorm, weighted
// sum, residual, LayerNorm.  grid (KQ, BATCH).
// ---------------------------------------------------------------------------
__global__ __launch_bounds__(256) void k_merge(
    const float* __restrict__ part, const float* __restrict__ rres,
    const float* __restrict__ gamma, const float* __restrict__ beta,
    float* __restrict__ out) {
    const int k = blockIdx.x;
    const int b = blockIdx.y;
    const int tid = threadIdx.x;

    __shared__ float pl[GRP * 68];
    __shared__ float fg[GRP];
    __shared__ float invS;
    __shared__ float vv[DDIM];
    __shared__ float stats[2];

    const float* src = part + ((size_t)(b * 64 + k)) * GRP * 68;
    for (int i = tid; i < GRP * 68; i += 256) pl[i] = src[i];
    __syncthreads();

    if (tid < GRP) {   // one wave: global max + renormalized sum
        const float m = pl[tid * 68 + 65];
        float M = m;
        for (int off = 32; off; off >>= 1) M = fmaxf(M, __shfl_xor(M, off));
        const float f = __expf(m - M);
        float S = pl[tid * 68 + 66] * f;
        for (int off = 32; off; off >>= 1) S += __shfl_xor(S, off);
        fg[tid] = f;
        if (tid == 0) invS = 1.0f / S;
    }
    __syncthreads();

    if (tid < DDIM) {
        float acc = 0.f;
        #pragma unroll 8
        for (int g = 0; g < GRP; ++g) acc = fmaf(pl[g * 68 + tid], fg[g], acc);
        vv[tid] = acc * invS + rres[b * DDIM + tid];
    }
    __syncthreads();

    if (tid < 64) {
        float a  = vv[tid] + (tid == 0 ? vv[64] : 0.f);
        float sq = vv[tid] * vv[tid] + (tid == 0 ? vv[64] * vv[64] : 0.f);
        for (int off = 32; off; off >>= 1) {
            a  += __shfl_down(a, off);
            sq += __shfl_down(sq, off);
        }
        if (tid == 0) {
            const float mu  = a * (1.0f / DDIM);
            const float var = sq * (1.0f / DDIM) - mu * mu;
            stats[0] = mu;
            stats[1] = rsqrtf(var + 1e-5f);
        }
    }
    __syncthreads();
    if (tid < DDIM) {
        out[((size_t)(b * 64 + k)) * DDIM + tid] =
            (vv[tid] - stats[0]) * stats[1] * gamma[tid] + beta[tid];
    }
}

// ---------------------------------------------------------------------------
extern "C" void kernel_launch(void* const* d_in, const int* in_sizes, int n_in,
                              void* d_out, int out_size, void* d_ws, size_t ws_size,
                              hipStream_t stream) {
    const float* x    = (const float*)d_in[0];
    const float* Wq1  = (const float*)d_in[1];
    const float* bq1  = (const float*)d_in[2];
    const float* Wq2  = (const float*)d_in[3];
    const float* bq2  = (const float*)d_in[4];
    const float* Wk   = (const float*)d_in[5];
    const float* bk   = (const float*)d_in[6];
    const float* Wv   = (const float*)d_in[7];
    const float* bv   = (const float*)d_in[8];
    const float* cq   = (const float*)d_in[9];
    const float* pos  = (const float*)d_in[10];
    const float* Wr   = (const float*)d_in[11];
    const float* br   = (const float*)d_in[12];
    const float* gamma= (const float*)d_in[13];
    const float* beta = (const float*)d_in[14];
    float* out = (float*)d_out;

    // workspace layout (byte offsets, all 16B-aligned)
    char* w8 = (char*)d_ws;
    float*  partial = (float*)w8;                    // 532480 B @0
    float*  rres    = (float*)(w8 + 532480);         // 8320 B
    float*  q64     = (float*)(w8 + 540800);         // 8192 B
    float*  hbuf    = (float*)(w8 + 548992);         // 8320 B
    __bf16* qbf     = (__bf16*)(w8 + 557312);        // 262144 B
    __bf16* WkT     = (__bf16*)(w8 + 819456);        // 10240 B
    __bf16* WvT     = (__bf16*)(w8 + 829696);        // 10240 B
    float*  posK    = (float*)(w8 + 839936);         // 17408 B
    float*  posV    = (float*)(w8 + 857344);         // 17680 B
    float*  wkc     = (float*)(w8 + 875024);         // 272 B
    float*  wvc     = (float*)(w8 + 875296);         // 272 B
    float*  part    = (float*)(w8 + 875568);         // 35651584 B  [b][k][g][68]

    k_prep<<<75, 256, 0, stream>>>(Wk, Wv, pos, WkT, WvT, posK, posV, wkc, wvc);
    k_gavg<<<dim3(64, BATCH), 256, 0, stream>>>(x, partial);
    k_qgen1<<<BATCH, 256, 0, stream>>>(partial, Wq1, bq1, Wr, br, hbuf, rres);
    k_qgen2<<<dim3(17, BATCH), 256, 0, stream>>>(hbuf, Wq2, bq2, qbf, q64);
    k_attn<<<dim3(GRP, BATCH), 256, 0, stream>>>(x, qbf, q64, WkT, WvT,
                                                 posK, posV, wkc, wvc,
                                                 bk, bv, cq, part);
    k_merge<<<dim3(KQ, BATCH), 256, 0, stream>>>(part, rres, gamma, beta, out);
}

// Round 4
// 671.176 us; speedup vs baseline: 1.1872x; 1.1872x over previous
//
#include <hip/hip_runtime.h>
#include <hip/hip_bf16.h>

// Problem constants
#define BATCH 32
#define NSEQ  16384
#define DDIM  65
#define CHUNK 64
#define KQ    64
#define NBLK  256          // NSEQ / CHUNK
#define SCALE 0.12403473458920847f   // 65^-0.5
#define TCH   4            // chunks per block (k_attn)
#define GRP   64           // NBLK / TCH  -> partial groups per batch
#define PST   80           // part row stride in floats (320 B, 64B-aligned)

typedef __bf16 bf16x8 __attribute__((ext_vector_type(8)));
typedef __bf16 bf16x4 __attribute__((ext_vector_type(4)));
typedef float  f32x4  __attribute__((ext_vector_type(4)));
#define MFMA16(a, b, c) __builtin_amdgcn_mfma_f32_16x16x32_bf16(a, b, c, 0, 0, 0)

__device__ __forceinline__ float gelu_exact(float v) {
    return 0.5f * v * (1.0f + erff(v * 0.7071067811865476f));
}

// tanh-approx GELU in sigmoid form: gelu = x * sigmoid(1.5957691x(1+0.044715x^2))
// |err| <= ~2e-4, far below bf16 rounding of keys/vals.
__device__ __forceinline__ float gelu_tanh(float x) {
    float x2 = x * x;
    float z  = x * fmaf(-0.07135481627f, x2, -1.59576912161f);  // -2t
    float e  = __expf(z);
    return x * __builtin_amdgcn_rcpf(e + 1.0f);
}

// ---------------------------------------------------------------------------
// Kernel 0: prep tables.
//  WkT bf16 [80][64]: row d<65 = Wk[e][d]; row 65 = Wv[e][64]; rest 0.
//    (packing Wv's last column lets one MFMA tile produce keys64 AND vals64)
//  WvT bf16 [80][64]: row d<65 = Wv[e][d]; rest 0.
//  posK f32 [64][68]: posK[c][d] = pos[c*65+d]
//  posV f32 [65][68]: posV[d][c] = pos[c*65+d]
//  wkc/wvc f32 [68]: column 64 of Wk / Wv
// ---------------------------------------------------------------------------
__global__ __launch_bounds__(256) void k_prep(const float* __restrict__ Wk,
                                              const float* __restrict__ Wv,
                                              const float* __restrict__ pos,
                                              __bf16* __restrict__ WkT,
                                              __bf16* __restrict__ WvT,
                                              float* __restrict__ posK,
                                              float* __restrict__ posV,
                                              float* __restrict__ wkc,
                                              float* __restrict__ wvc) {
    int i = blockIdx.x * 256 + threadIdx.x;
    if (i < 10240) {
        int m = i / 5120;
        int j = i - m * 5120;
        int d = j >> 6, e = j & 63;
        if (m == 0) {
            float v = 0.f;
            if (d < DDIM)       v = Wk[e * DDIM + d];
            else if (d == 65)   v = Wv[e * DDIM + 64];
            WkT[(size_t)d * 64 + e] = (__bf16)v;
        } else {
            WvT[(size_t)d * 64 + e] =
                (d < DDIM) ? (__bf16)Wv[e * DDIM + d] : (__bf16)0.0f;
        }
    } else if (i < 14592) {
        int j = i - 10240;
        int c = j / 68, d = j - c * 68;
        posK[j] = (d < DDIM) ? pos[c * DDIM + d] : 0.f;
    } else if (i < 19012) {
        int j = i - 14592;
        int d = j / 68, c = j - d * 68;
        posV[j] = (d < DDIM && c < 64) ? pos[c * DDIM + d] : 0.f;
    } else if (i < 19080) {
        int d = i - 19012;
        wkc[d] = (d < DDIM) ? Wk[64 * DDIM + d] : 0.f;
    } else if (i < 19148) {
        int d = i - 19080;
        wvc[d] = (d < DDIM) ? Wv[64 * DDIM + d] : 0.f;
    }
}

// ---------------------------------------------------------------------------
// Kernel 1: per-slice partial sums over N.  grid (64, 32).
// ---------------------------------------------------------------------------
__global__ __launch_bounds__(256) void k_gavg(const float* __restrict__ x,
                                              float* __restrict__ partial) {
    const int s = blockIdx.x;
    const int b = blockIdx.y;
    const int tid = threadIdx.x;
    const int w = tid >> 6, lane = tid & 63;
    const float* xb = x + (size_t)b * NSEQ * DDIM;
    const int n0 = s * 256;
    float acc = 0.f, acce = 0.f;
    #pragma unroll 4
    for (int i = 0; i < 64; ++i) {
        const float* row = xb + (size_t)(n0 + w + i * 4) * DDIM;
        acc  += row[lane];
        acce += row[64];
    }
    __shared__ float part[4][DDIM];
    part[w][lane] = acc;
    if (lane == 0) part[w][64] = acce;
    __syncthreads();
    if (tid < DDIM) {
        partial[((size_t)b * 64 + s) * DDIM + tid] =
            part[0][tid] + part[1][tid] + part[2][tid] + part[3][tid];
    }
}

// ---------------------------------------------------------------------------
// Kernel 2a: reduce partials -> gavg; h = gelu(gavg@Wq1+bq1); r = gavg@Wr+br.
// ---------------------------------------------------------------------------
__global__ __launch_bounds__(256) void k_qgen1(const float* __restrict__ partial,
    const float* __restrict__ Wq1, const float* __restrict__ bq1,
    const float* __restrict__ Wr,  const float* __restrict__ br,
    float* __restrict__ h_out, float* __restrict__ r_out) {
    const int b = blockIdx.x, tid = threadIdx.x;
    __shared__ float g[DDIM];
    if (tid < DDIM) {
        float a = 0.f;
        const float* p = partial + (size_t)b * 64 * DDIM + tid;
        #pragma unroll 8
        for (int s = 0; s < 64; ++s) a += p[s * DDIM];
        g[tid] = a * (1.0f / 16384.0f);
    }
    __syncthreads();
    if (tid < DDIM) {
        float a = bq1[tid];
        for (int e = 0; e < DDIM; ++e) a += g[e] * Wq1[e * DDIM + tid];
        h_out[b * DDIM + tid] = gelu_exact(a);
    } else if (tid >= 128 && tid < 128 + DDIM) {
        const int d = tid - 128;
        float a = br[d];
        for (int e = 0; e < DDIM; ++e) a += g[e] * Wr[e * DDIM + d];
        r_out[b * DDIM + d] = a;
    }
}

// ---------------------------------------------------------------------------
// Kernel 2b: q = (h@Wq2+bq2)*SCALE -> qbf [64][64] bf16 + q64 col.
// ---------------------------------------------------------------------------
__global__ __launch_bounds__(256) void k_qgen2(const float* __restrict__ h_in,
    const float* __restrict__ Wq2, const float* __restrict__ bq2,
    __bf16* __restrict__ qbf, float* __restrict__ q64) {
    const int b = blockIdx.y, tid = threadIdx.x;
    const int o = blockIdx.x * 256 + tid;
    __shared__ float h[DDIM];
    if (tid < DDIM) h[tid] = h_in[b * DDIM + tid];
    __syncthreads();
    if (o >= KQ * DDIM) return;
    float a = bq2[o];
    #pragma unroll 13
    for (int e = 0; e < DDIM; ++e) a += h[e] * Wq2[e * (KQ * DDIM) + o];
    a *= SCALE;
    const int k = o / DDIM, d = o - k * DDIM;
    if (d < 64) qbf[(size_t)b * 4096 + k * 64 + d] = (__bf16)a;
    else        q64[b * 64 + k] = a;
}

// ---------------------------------------------------------------------------
// Kernel 3 (MFMA): grid (GRP=64, BATCH).  TCH=4 chunks per block with online
// cross-softmax state (m, s, O[65]) in registers.  No register prefetch of x
// (round-3 spill source); x staged at loop top like the proven round-2 body.
// WkT row-65 packing: the mt=4 keys tile yields keys[c][64] (r=0) and
// vals[c][64] (r=1), so vals needs only 4 tiles.  2 barriers/chunk.
// ---------------------------------------------------------------------------
__global__ __launch_bounds__(256, 4) void k_attn(
    const float* __restrict__ x,
    const __bf16* __restrict__ qbf, const float* __restrict__ q64g,
    const __bf16* __restrict__ WkT, const __bf16* __restrict__ WvT,
    const float* __restrict__ posK, const float* __restrict__ posV,
    const float* __restrict__ wkc, const float* __restrict__ wvc,
    const float* __restrict__ bkb, const float* __restrict__ bvb,
    const float* __restrict__ cq,
    float* __restrict__ part) {
    const int g  = blockIdx.x;
    const int b  = blockIdx.y;
    const int nb0 = g * TCH;
    const int tid = threadIdx.x;
    const int lane = tid & 63, w = tid >> 6;
    const int l16 = lane & 15, quad = lane >> 4;

    __shared__ __align__(16) __bf16 xP[64 * 64];     // x chunk, then P (swizzled)
    __shared__ __align__(16) __bf16 keysL[64 * 64];  // [c][d0..63] swizzled
    __shared__ __align__(16) __bf16 valsT[64 * 64];  // [d][c0..63] swizzled
    __shared__ __align__(16) __bf16 kcol64[64];      // keys[c][64]
    __shared__ __align__(16) __bf16 vcol64[64];      // vals[c][64]
    __shared__ float xs64[64];                       // x[c][64] fp32

    // hoisted q fragments (loop-invariant)
    const int krow = w * 16 + l16;                   // this lane's k
    const __bf16* qr = qbf + (size_t)b * 4096 + krow * 64 + quad * 8;
    bf16x8 q0 = *(const bf16x8*)qr;
    bf16x8 q1 = *(const bf16x8*)(qr + 32);
    const float q64k = q64g[b * 64 + krow];
    const float cq64 = cq[64];

    // online cross-softmax state (per lane: k = krow, d = mt*16+quad*4+r)
    f32x4 O[4];
    #pragma unroll
    for (int mt = 0; mt < 4; ++mt) O[mt] = f32x4{0.f, 0.f, 0.f, 0.f};
    float O64 = 0.f, mrun = -1e30f, srun = 0.f;

    // staging mapping: thread -> (row cst, quarter gst); rows owned by wave.
    const int cst = tid >> 2, gst = tid & 3;
    const int swst = (cst & 7) << 4;

    for (int t = 0; t < TCH; ++t) {
        // ---- stage x chunk t: f32 global -> swizzled bf16 xP (own rows) ----
        {
            const float* xrow =
                x + ((size_t)b * NSEQ + (size_t)(nb0 + t) * CHUNK + cst) * DDIM;
            char* dst = (char*)xP + cst * 128;
            #pragma unroll
            for (int j = 0; j < 16; ++j) {
                const int e = gst + 4 * j;
                *(__bf16*)(dst + ((((e >> 3) << 4) ^ swst) + (e & 7) * 2)) =
                    (__bf16)xrow[e];
            }
            if (gst == 0) xs64[cst] = xrow[64];
        }
        __syncthreads();   // BAR_A (also protects keysL/valsT reuse)

        // ---- ph2: keys/vals via MFMA + gelu, written pre-transposed ----
        {
            const int crow = w * 16 + l16;
            const int sw_c = (crow & 7) << 4;
            const char* xrow = (const char*)xP + crow * 128;
            bf16x8 x0 = *(const bf16x8*)(xrow + ((quad * 16) ^ sw_c));
            bf16x8 x1 = *(const bf16x8*)(xrow + ((quad * 16 + 64) ^ sw_c));
            const float xe_c = xs64[crow];
            const f32x4 z = {0.f, 0.f, 0.f, 0.f};

            // keys (+packed col64 rows): A=WkT (m=d), B=x (n=c)
            f32x4 kacc[5];
            #pragma unroll
            for (int mt = 0; mt < 5; ++mt) {
                const __bf16* wr = WkT + (mt * 16 + l16) * 64 + quad * 8;
                kacc[mt] = MFMA16(*(const bf16x8*)wr, x0, z);
                kacc[mt] = MFMA16(*(const bf16x8*)(wr + 32), x1, kacc[mt]);
            }
            #pragma unroll
            for (int mt = 0; mt < 4; ++mt) {
                const int d0 = mt * 16 + quad * 4;
                const f32x4 pk  = *(const f32x4*)(posK + crow * 68 + d0);
                const f32x4 wk4 = *(const f32x4*)(wkc + d0);
                const f32x4 bk4 = *(const f32x4*)(bkb + d0);
                bf16x4 kv;
                #pragma unroll
                for (int r = 0; r < 4; ++r) {
                    const float pre = kacc[mt][r] + xe_c * wk4[r] + bk4[r];
                    kv[r] = (__bf16)(gelu_tanh(pre) + pk[r]);
                }
                *(bf16x4*)((char*)keysL + crow * 128 + ((d0 * 2) ^ sw_c)) = kv;
            }
            if (quad == 0) {
                // r=0 -> keys[crow][64];  r=1 -> vals[crow][64] (packed row 65)
                const float prek = kacc[4][0] + xe_c * wkc[64] + bkb[64];
                kcol64[crow] = (__bf16)(gelu_tanh(prek) + posK[crow * 68 + 64]);
                const float prev = kacc[4][1] + xe_c * wvc[64] + bvb[64];
                vcol64[crow] = (__bf16)(gelu_tanh(prev) + posK[crow * 68 + 64]);
            }

            // vals (d<64 only): A=x (m=c), B=WvT (n=d)
            f32x4 vacc[4];
            #pragma unroll
            for (int nt = 0; nt < 4; ++nt) {
                const __bf16* wr = WvT + (nt * 16 + l16) * 64 + quad * 8;
                vacc[nt] = MFMA16(x0, *(const bf16x8*)wr, z);
                vacc[nt] = MFMA16(x1, *(const bf16x8*)(wr + 32), vacc[nt]);
            }
            const int cv0 = w * 16 + quad * 4;
            float xe4[4];
            #pragma unroll
            for (int r = 0; r < 4; ++r) xe4[r] = xs64[cv0 + r];
            #pragma unroll
            for (int nt = 0; nt < 4; ++nt) {
                const int d = nt * 16 + l16;
                const float wvd = wvc[d], bvd = bvb[d];
                const f32x4 pv = *(const f32x4*)(posV + d * 68 + cv0);
                bf16x4 vv;
                #pragma unroll
                for (int r = 0; r < 4; ++r) {
                    const float pre = vacc[nt][r] + xe4[r] * wvd + bvd;
                    vv[r] = (__bf16)(gelu_tanh(pre) + pv[r]);
                }
                *(bf16x4*)((char*)valsT + d * 128 + ((cv0 * 2) ^ ((d & 7) << 4))) = vv;
            }
        }
        __syncthreads();   // BAR_B

        // ---- ph3: S^T, lane-local softmax over c, P store, d=64 column ----
        float inv_k, o64n;
        {
            const f32x4 z = {0.f, 0.f, 0.f, 0.f};
            float st[4][4];
            #pragma unroll
            for (int mt = 0; mt < 4; ++mt) {
                const int cA = mt * 16 + l16;
                const char* kr = (const char*)keysL + cA * 128;
                const int swc = (cA & 7) << 4;
                f32x4 s = MFMA16(*(const bf16x8*)(kr + ((quad * 16) ^ swc)), q0, z);
                s = MFMA16(*(const bf16x8*)(kr + ((quad * 16 + 64) ^ swc)), q1, s);
                bf16x4 k4 = *(const bf16x4*)((const char*)kcol64 + (mt * 16 + quad * 4) * 2);
                #pragma unroll
                for (int r = 0; r < 4; ++r)
                    st[mt][r] = fmaf(q64k, (float)k4[r], s[r]) * SCALE;
            }
            float m = st[0][0];
            #pragma unroll
            for (int mt = 0; mt < 4; ++mt)
                #pragma unroll
                for (int r = 0; r < 4; ++r) m = fmaxf(m, st[mt][r]);
            m = fmaxf(m, __shfl_xor(m, 16));
            m = fmaxf(m, __shfl_xor(m, 32));
            float sum = 0.f;
            #pragma unroll
            for (int mt = 0; mt < 4; ++mt)
                #pragma unroll
                for (int r = 0; r < 4; ++r) {
                    st[mt][r] = __expf(st[mt][r] - m);
                    sum += st[mt][r];
                }
            sum += __shfl_xor(sum, 16);
            sum += __shfl_xor(sum, 32);
            inv_k = __builtin_amdgcn_rcpf(sum);

            // store unnormalized P into own k-row of xP (swizzled)
            const int swk = (krow & 7) << 4;
            char* prow = (char*)xP + krow * 128;
            #pragma unroll
            for (int mt = 0; mt < 4; ++mt) {
                bf16x4 p4;
                #pragma unroll
                for (int r = 0; r < 4; ++r) p4[r] = (__bf16)st[mt][r];
                *(bf16x4*)(prow + (((mt * 16 + quad * 4) * 2) ^ swk)) = p4;
            }

            // d=64 output column from fp32 P
            float o = 0.f;
            #pragma unroll
            for (int mt = 0; mt < 4; ++mt) {
                bf16x4 v4 = *(const bf16x4*)((const char*)vcol64 + (mt * 16 + quad * 4) * 2);
                #pragma unroll
                for (int r = 0; r < 4; ++r) o = fmaf(st[mt][r], (float)v4[r], o);
            }
            o += __shfl_xor(o, 16);
            o += __shfl_xor(o, 32);
            o64n = o * inv_k;
        }
        // NO barrier: each wave reads back only the P rows it wrote.

        // ---- ph4: blk^T = valsT@P (kept in regs) + cs, online update ----
        {
            const f32x4 z = {0.f, 0.f, 0.f, 0.f};
            const int swk = (krow & 7) << 4;
            const char* prow = (const char*)xP + krow * 128;
            bf16x8 p0 = *(const bf16x8*)(prow + ((quad * 16) ^ swk));
            bf16x8 p1 = *(const bf16x8*)(prow + ((quad * 16 + 64) ^ swk));
            f32x4 oo[4];
            float csp = 0.f;
            #pragma unroll
            for (int mt = 0; mt < 4; ++mt) {
                const int dA = mt * 16 + l16;
                const char* vr = (const char*)valsT + dA * 128;
                const int swd = (dA & 7) << 4;
                f32x4 o = MFMA16(*(const bf16x8*)(vr + ((quad * 16) ^ swd)), p0, z);
                o = MFMA16(*(const bf16x8*)(vr + ((quad * 16 + 64) ^ swd)), p1, o);
                oo[mt] = o;
                const int d0 = mt * 16 + quad * 4;
                const f32x4 cq4 = *(const f32x4*)(cq + d0);
                #pragma unroll
                for (int r = 0; r < 4; ++r) csp = fmaf(o[r], cq4[r], csp);
            }
            csp += __shfl_xor(csp, 16);
            csp += __shfl_xor(csp, 32);
            const float cs = (csp * inv_k + cq64 * o64n) * SCALE;

            // online cross-softmax accumulate
            const float mn = fmaxf(mrun, cs);
            const float a  = __expf(mrun - mn);
            const float e  = __expf(cs - mn);
            srun = srun * a + e;
            const float ei = e * inv_k;
            #pragma unroll
            for (int mt = 0; mt < 4; ++mt)
                #pragma unroll
                for (int r = 0; r < 4; ++r)
                    O[mt][r] = O[mt][r] * a + oo[mt][r] * ei;
            O64 = O64 * a + o64n * e;
            mrun = mn;
        }
    }

    // ---- store partial: part[b][k][g][PST] = {O[0..64], m, s, pad} ----
    {
        float* dst = part + (((size_t)(b * 64 + krow)) * GRP + g) * PST;
        #pragma unroll
        for (int mt = 0; mt < 4; ++mt)
            *(f32x4*)(dst + mt * 16 + quad * 4) = O[mt];
        if (quad == 0) {
            f32x4 tail = {O64, mrun, srun, 0.f};
            *(f32x4*)(dst + 64) = tail;
        }
    }
}

// ---------------------------------------------------------------------------
// Kernel 4: merge GRP partials per (b,k): global softmax renorm, weighted
// sum, residual, LayerNorm.  grid (KQ, BATCH).
// ---------------------------------------------------------------------------
__global__ __launch_bounds__(256) void k_merge(
    const float* __restrict__ part, const float* __restrict__ rres,
    const float* __restrict__ gamma, const float* __restrict__ beta,
    float* __restrict__ out) {
    const int k = blockIdx.x;
    const int b = blockIdx.y;
    const int tid = threadIdx.x;

    __shared__ float pl[GRP * PST];
    __shared__ float fg[GRP];
    __shared__ float invS;
    __shared__ float vv[DDIM];
    __shared__ float stats[2];

    const float* src = part + ((size_t)(b * 64 + k)) * GRP * PST;
    for (int i = tid; i < GRP * PST; i += 256) pl[i] = src[i];
    __syncthreads();

    if (tid < GRP) {   // one wave: global max + renormalized sum
        const float m = pl[tid * PST + 65];
        float M = m;
        for (int off = 32; off; off >>= 1) M = fmaxf(M, __shfl_xor(M, off));
        const float f = __expf(m - M);
        float S = pl[tid * PST + 66] * f;
        for (int off = 32; off; off >>= 1) S += __shfl_xor(S, off);
        fg[tid] = f;
        if (tid == 0) invS = 1.0f / S;
    }
    __syncthreads();

    if (tid < DDIM) {
        float acc = 0.f;
        #pragma unroll 8
        for (int g = 0; g < GRP; ++g) acc = fmaf(pl[g * PST + tid], fg[g], acc);
        vv[tid] = acc * invS + rres[b * DDIM + tid];
    }
    __syncthreads();

    if (tid < 64) {
        float a  = vv[tid] + (tid == 0 ? vv[64] : 0.f);
        float sq = vv[tid] * vv[tid] + (tid == 0 ? vv[64] * vv[64] : 0.f);
        for (int off = 32; off; off >>= 1) {
            a  += __shfl_down(a, off);
            sq += __shfl_down(sq, off);
        }
        if (tid == 0) {
            const float mu  = a * (1.0f / DDIM);
            const float var = sq * (1.0f / DDIM) - mu * mu;
            stats[0] = mu;
            stats[1] = rsqrtf(var + 1e-5f);
        }
    }
    __syncthreads();
    if (tid < DDIM) {
        out[((size_t)(b * 64 + k)) * DDIM + tid] =
            (vv[tid] - stats[0]) * stats[1] * gamma[tid] + beta[tid];
    }
}

// ---------------------------------------------------------------------------
extern "C" void kernel_launch(void* const* d_in, const int* in_sizes, int n_in,
                              void* d_out, int out_size, void* d_ws, size_t ws_size,
                              hipStream_t stream) {
    const float* x    = (const float*)d_in[0];
    const float* Wq1  = (const float*)d_in[1];
    const float* bq1  = (const float*)d_in[2];
    const float* Wq2  = (const float*)d_in[3];
    const float* bq2  = (const float*)d_in[4];
    const float* Wk   = (const float*)d_in[5];
    const float* bk   = (const float*)d_in[6];
    const float* Wv   = (const float*)d_in[7];
    const float* bv   = (const float*)d_in[8];
    const float* cq   = (const float*)d_in[9];
    const float* pos  = (const float*)d_in[10];
    const float* Wr   = (const float*)d_in[11];
    const float* br   = (const float*)d_in[12];
    const float* gamma= (const float*)d_in[13];
    const float* beta = (const float*)d_in[14];
    float* out = (float*)d_out;

    // workspace layout (byte offsets, all 16B-aligned)
    char* w8 = (char*)d_ws;
    float*  partial = (float*)w8;                    // 532480 B @0
    float*  rres    = (float*)(w8 + 532480);         // 8320 B
    float*  q64     = (float*)(w8 + 540800);         // 8192 B
    float*  hbuf    = (float*)(w8 + 548992);         // 8320 B
    __bf16* qbf     = (__bf16*)(w8 + 557312);        // 262144 B
    __bf16* WkT     = (__bf16*)(w8 + 819456);        // 10240 B
    __bf16* WvT     = (__bf16*)(w8 + 829696);        // 10240 B
    float*  posK    = (float*)(w8 + 839936);         // 17408 B
    float*  posV    = (float*)(w8 + 857344);         // 17680 B
    float*  wkc     = (float*)(w8 + 875024);         // 272 B
    float*  wvc     = (float*)(w8 + 875296);         // 272 B
    float*  part    = (float*)(w8 + 875568);         // 41943040 B [b][k][g][80]

    k_prep<<<75, 256, 0, stream>>>(Wk, Wv, pos, WkT, WvT, posK, posV, wkc, wvc);
    k_gavg<<<dim3(64, BATCH), 256, 0, stream>>>(x, partial);
    k_qgen1<<<BATCH, 256, 0, stream>>>(partial, Wq1, bq1, Wr, br, hbuf, rres);
    k_qgen2<<<dim3(17, BATCH), 256, 0, stream>>>(hbuf, Wq2, bq2, qbf, q64);
    k_attn<<<dim3(GRP, BATCH), 256, 0, stream>>>(x, qbf, q64, WkT, WvT,
                                                 posK, posV, wkc, wvc,
                                                 bk, bv, cq, part);
    k_merge<<<dim3(KQ, BATCH), 256, 0, stream>>>(part, rres, gamma, beta, out);
}

// Round 5
// 564.990 us; speedup vs baseline: 1.4103x; 1.1879x over previous
//
#include <hip/hip_runtime.h>
#include <hip/hip_bf16.h>

// Problem constants
#define BATCH 32
#define NSEQ  16384
#define DDIM  65
#define CHUNK 64
#define KQ    64
#define NBLK  256          // NSEQ / CHUNK
#define SCALE 0.12403473458920847f   // 65^-0.5
#define TCH   4            // chunks per block (k_attn)
#define GRP   64           // NBLK / TCH  -> partial groups per batch
#define PST   80           // part row stride in floats (320 B, 64B-aligned)

typedef __bf16 bf16x8 __attribute__((ext_vector_type(8)));
typedef __bf16 bf16x4 __attribute__((ext_vector_type(4)));
typedef float  f32x4  __attribute__((ext_vector_type(4)));
#define MFMA16(a, b, c) __builtin_amdgcn_mfma_f32_16x16x32_bf16(a, b, c, 0, 0, 0)

__device__ __forceinline__ float gelu_exact(float v) {
    return 0.5f * v * (1.0f + erff(v * 0.7071067811865476f));
}

// tanh-approx GELU in sigmoid form: gelu = x * sigmoid(1.5957691x(1+0.044715x^2))
// |err| <= ~2e-4, far below bf16 rounding of keys/vals.
__device__ __forceinline__ float gelu_tanh(float x) {
    float x2 = x * x;
    float z  = x * fmaf(-0.07135481627f, x2, -1.59576912161f);  // -2t
    float e  = __expf(z);
    return x * __builtin_amdgcn_rcpf(e + 1.0f);
}

// ---------------------------------------------------------------------------
// Kernel 0: prep tables.
//  WkT bf16 [80][64]: row d<65 = Wk[e][d]; row 65 = Wv[e][64]; rest 0.
//  WvT bf16 [80][64]: row d<65 = Wv[e][d]; rest 0.
//  posK f32 [64][68]: posK[c][d] = pos[c*65+d]
//  posV f32 [65][68]: posV[d][c] = pos[c*65+d]
//  wkc/wvc f32 [68]: column 64 of Wk / Wv
// ---------------------------------------------------------------------------
__global__ __launch_bounds__(256) void k_prep(const float* __restrict__ Wk,
                                              const float* __restrict__ Wv,
                                              const float* __restrict__ pos,
                                              __bf16* __restrict__ WkT,
                                              __bf16* __restrict__ WvT,
                                              float* __restrict__ posK,
                                              float* __restrict__ posV,
                                              float* __restrict__ wkc,
                                              float* __restrict__ wvc) {
    int i = blockIdx.x * 256 + threadIdx.x;
    if (i < 10240) {
        int m = i / 5120;
        int j = i - m * 5120;
        int d = j >> 6, e = j & 63;
        if (m == 0) {
            float v = 0.f;
            if (d < DDIM)       v = Wk[e * DDIM + d];
            else if (d == 65)   v = Wv[e * DDIM + 64];
            WkT[(size_t)d * 64 + e] = (__bf16)v;
        } else {
            WvT[(size_t)d * 64 + e] =
                (d < DDIM) ? (__bf16)Wv[e * DDIM + d] : (__bf16)0.0f;
        }
    } else if (i < 14592) {
        int j = i - 10240;
        int c = j / 68, d = j - c * 68;
        posK[j] = (d < DDIM) ? pos[c * DDIM + d] : 0.f;
    } else if (i < 19012) {
        int j = i - 14592;
        int d = j / 68, c = j - d * 68;
        posV[j] = (d < DDIM && c < 64) ? pos[c * DDIM + d] : 0.f;
    } else if (i < 19080) {
        int d = i - 19012;
        wkc[d] = (d < DDIM) ? Wk[64 * DDIM + d] : 0.f;
    } else if (i < 19148) {
        int d = i - 19080;
        wvc[d] = (d < DDIM) ? Wv[64 * DDIM + d] : 0.f;
    }
}

// ---------------------------------------------------------------------------
// Kernel 1: per-slice partial sums over N.  grid (64, 32).
// ---------------------------------------------------------------------------
__global__ __launch_bounds__(256) void k_gavg(const float* __restrict__ x,
                                              float* __restrict__ partial) {
    const int s = blockIdx.x;
    const int b = blockIdx.y;
    const int tid = threadIdx.x;
    const int w = tid >> 6, lane = tid & 63;
    const float* xb = x + (size_t)b * NSEQ * DDIM;
    const int n0 = s * 256;
    float acc = 0.f, acce = 0.f;
    #pragma unroll 4
    for (int i = 0; i < 64; ++i) {
        const float* row = xb + (size_t)(n0 + w + i * 4) * DDIM;
        acc  += row[lane];
        acce += row[64];
    }
    __shared__ float part[4][DDIM];
    part[w][lane] = acc;
    if (lane == 0) part[w][64] = acce;
    __syncthreads();
    if (tid < DDIM) {
        partial[((size_t)b * 64 + s) * DDIM + tid] =
            part[0][tid] + part[1][tid] + part[2][tid] + part[3][tid];
    }
}

// ---------------------------------------------------------------------------
// Kernel 2a: reduce partials -> gavg; h = gelu(gavg@Wq1+bq1); r = gavg@Wr+br.
// ---------------------------------------------------------------------------
__global__ __launch_bounds__(256) void k_qgen1(const float* __restrict__ partial,
    const float* __restrict__ Wq1, const float* __restrict__ bq1,
    const float* __restrict__ Wr,  const float* __restrict__ br,
    float* __restrict__ h_out, float* __restrict__ r_out) {
    const int b = blockIdx.x, tid = threadIdx.x;
    __shared__ float g[DDIM];
    if (tid < DDIM) {
        float a = 0.f;
        const float* p = partial + (size_t)b * 64 * DDIM + tid;
        #pragma unroll 8
        for (int s = 0; s < 64; ++s) a += p[s * DDIM];
        g[tid] = a * (1.0f / 16384.0f);
    }
    __syncthreads();
    if (tid < DDIM) {
        float a = bq1[tid];
        for (int e = 0; e < DDIM; ++e) a += g[e] * Wq1[e * DDIM + tid];
        h_out[b * DDIM + tid] = gelu_exact(a);
    } else if (tid >= 128 && tid < 128 + DDIM) {
        const int d = tid - 128;
        float a = br[d];
        for (int e = 0; e < DDIM; ++e) a += g[e] * Wr[e * DDIM + d];
        r_out[b * DDIM + d] = a;
    }
}

// ---------------------------------------------------------------------------
// Kernel 2b: q = (h@Wq2+bq2)*SCALE -> qbf [64][64] bf16 + q64 col.
// ---------------------------------------------------------------------------
__global__ __launch_bounds__(256) void k_qgen2(const float* __restrict__ h_in,
    const float* __restrict__ Wq2, const float* __restrict__ bq2,
    __bf16* __restrict__ qbf, float* __restrict__ q64) {
    const int b = blockIdx.y, tid = threadIdx.x;
    const int o = blockIdx.x * 256 + tid;
    __shared__ float h[DDIM];
    if (tid < DDIM) h[tid] = h_in[b * DDIM + tid];
    __syncthreads();
    if (o >= KQ * DDIM) return;
    float a = bq2[o];
    #pragma unroll 13
    for (int e = 0; e < DDIM; ++e) a += h[e] * Wq2[e * (KQ * DDIM) + o];
    a *= SCALE;
    const int k = o / DDIM, d = o - k * DDIM;
    if (d < 64) qbf[(size_t)b * 4096 + k * 64 + d] = (__bf16)a;
    else        q64[b * 64 + k] = a;
}

// ---------------------------------------------------------------------------
// Kernel 3 (MFMA): grid (GRP=64, BATCH).  TCH=4 chunks/block, online
// cross-softmax.  Register-pressure redesign vs round 4:
//  * vq[c] = vals[c][:64]·cq computed in ph2 (from in-register values,
//    16 shuffles) -> cs known in ph3 BEFORE PV.
//  * P stored to LDS pre-scaled by ei; O pre-scaled by a; PV accumulates
//    directly into O via the MFMA C operand.  ph4 live set = {p0,p1,O}.
//  * __launch_bounds__(256,3): reg cap 170, no spill.
// ---------------------------------------------------------------------------
__global__ __launch_bounds__(256, 3) void k_attn(
    const float* __restrict__ x,
    const __bf16* __restrict__ qbf, const float* __restrict__ q64g,
    const __bf16* __restrict__ WkT, const __bf16* __restrict__ WvT,
    const float* __restrict__ posK, const float* __restrict__ posV,
    const float* __restrict__ wkc, const float* __restrict__ wvc,
    const float* __restrict__ bkb, const float* __restrict__ bvb,
    const float* __restrict__ cq,
    float* __restrict__ part) {
    const int g  = blockIdx.x;
    const int b  = blockIdx.y;
    const int nb0 = g * TCH;
    const int tid = threadIdx.x;
    const int lane = tid & 63, w = tid >> 6;
    const int l16 = lane & 15, quad = lane >> 4;

    __shared__ __align__(16) __bf16 xP[64 * 64];     // x chunk, then P (swizzled)
    __shared__ __align__(16) __bf16 keysL[64 * 64];  // [c][d0..63] swizzled
    __shared__ __align__(16) __bf16 valsT[64 * 64];  // [d][c0..63] swizzled
    __shared__ __align__(16) __bf16 kcol64[64];      // keys[c][64]
    __shared__ __align__(16) __bf16 vcol64[64];      // vals[c][64]
    __shared__ __align__(16) float vq[64];           // vals[c][:64]·cq
    __shared__ float xs64[64];                       // x[c][64] fp32

    // hoisted q fragments (loop-invariant)
    const int krow = w * 16 + l16;                   // this lane's k
    const __bf16* qr = qbf + (size_t)b * 4096 + krow * 64 + quad * 8;
    bf16x8 q0 = *(const bf16x8*)qr;
    bf16x8 q1 = *(const bf16x8*)(qr + 32);
    const float q64k = q64g[b * 64 + krow];
    const float cq64 = cq[64];

    // online cross-softmax state (per lane: k = krow, d = mt*16+quad*4+r)
    f32x4 O[4];
    #pragma unroll
    for (int mt = 0; mt < 4; ++mt) O[mt] = f32x4{0.f, 0.f, 0.f, 0.f};
    float O64 = 0.f, mrun = -1e30f, srun = 0.f;

    // staging mapping: thread -> (row cst, quarter gst); rows owned by wave.
    const int cst = tid >> 2, gst = tid & 3;
    const int swst = (cst & 7) << 4;

    for (int t = 0; t < TCH; ++t) {
        // ---- stage x chunk t: f32 global -> swizzled bf16 xP (own rows) ----
        {
            const float* xrow =
                x + ((size_t)b * NSEQ + (size_t)(nb0 + t) * CHUNK + cst) * DDIM;
            char* dst = (char*)xP + cst * 128;
            #pragma unroll
            for (int j = 0; j < 16; ++j) {
                const int e = gst + 4 * j;
                *(__bf16*)(dst + ((((e >> 3) << 4) ^ swst) + (e & 7) * 2)) =
                    (__bf16)xrow[e];
            }
            if (gst == 0) xs64[cst] = xrow[64];
        }
        __syncthreads();   // BAR_A (also protects keysL/valsT/vq reuse)

        // ---- ph2: keys/vals via MFMA + gelu, pre-transposed; vq built ----
        {
            const int crow = w * 16 + l16;
            const int sw_c = (crow & 7) << 4;
            const char* xrow = (const char*)xP + crow * 128;
            bf16x8 x0 = *(const bf16x8*)(xrow + ((quad * 16) ^ sw_c));
            bf16x8 x1 = *(const bf16x8*)(xrow + ((quad * 16 + 64) ^ sw_c));
            const float xe_c = xs64[crow];
            const f32x4 z = {0.f, 0.f, 0.f, 0.f};

            // keys (+packed col64 rows): A=WkT (m=d), B=x (n=c)
            f32x4 kacc[5];
            #pragma unroll
            for (int mt = 0; mt < 5; ++mt) {
                const __bf16* wr = WkT + (mt * 16 + l16) * 64 + quad * 8;
                kacc[mt] = MFMA16(*(const bf16x8*)wr, x0, z);
                kacc[mt] = MFMA16(*(const bf16x8*)(wr + 32), x1, kacc[mt]);
            }
            #pragma unroll
            for (int mt = 0; mt < 4; ++mt) {
                const int d0 = mt * 16 + quad * 4;
                const f32x4 pk  = *(const f32x4*)(posK + crow * 68 + d0);
                const f32x4 wk4 = *(const f32x4*)(wkc + d0);
                const f32x4 bk4 = *(const f32x4*)(bkb + d0);
                bf16x4 kv;
                #pragma unroll
                for (int r = 0; r < 4; ++r) {
                    const float pre = kacc[mt][r] + xe_c * wk4[r] + bk4[r];
                    kv[r] = (__bf16)(gelu_tanh(pre) + pk[r]);
                }
                *(bf16x4*)((char*)keysL + crow * 128 + ((d0 * 2) ^ sw_c)) = kv;
            }
            if (quad == 0) {
                // r=0 -> keys[crow][64];  r=1 -> vals[crow][64] (packed row 65)
                const float prek = kacc[4][0] + xe_c * wkc[64] + bkb[64];
                kcol64[crow] = (__bf16)(gelu_tanh(prek) + posK[crow * 68 + 64]);
                const float prev = kacc[4][1] + xe_c * wvc[64] + bvb[64];
                vcol64[crow] = (__bf16)(gelu_tanh(prev) + posK[crow * 68 + 64]);
            }

            // vals (d<64): A=x (m=c), B=WvT (n=d); accumulate vq partials
            const int cv0 = w * 16 + quad * 4;
            float xe4[4];
            #pragma unroll
            for (int r = 0; r < 4; ++r) xe4[r] = xs64[cv0 + r];
            float vqp[4] = {0.f, 0.f, 0.f, 0.f};
            #pragma unroll
            for (int nt = 0; nt < 4; ++nt) {
                const __bf16* wr = WvT + (nt * 16 + l16) * 64 + quad * 8;
                f32x4 vacc = MFMA16(x0, *(const bf16x8*)wr, z);
                vacc = MFMA16(x1, *(const bf16x8*)(wr + 32), vacc);
                const int d = nt * 16 + l16;
                const float wvd = wvc[d], bvd = bvb[d];
                const float cqd = cq[d];
                const f32x4 pv = *(const f32x4*)(posV + d * 68 + cv0);
                bf16x4 vv;
                #pragma unroll
                for (int r = 0; r < 4; ++r) {
                    const float pre = vacc[r] + xe4[r] * wvd + bvd;
                    const __bf16 vb = (__bf16)(gelu_tanh(pre) + pv[r]);
                    vv[r] = vb;
                    vqp[r] = fmaf((float)vb, cqd, vqp[r]);
                }
                *(bf16x4*)((char*)valsT + d * 128 + ((cv0 * 2) ^ ((d & 7) << 4))) = vv;
            }
            // reduce vq partials over l16 and publish
            #pragma unroll
            for (int r = 0; r < 4; ++r) {
                vqp[r] += __shfl_xor(vqp[r], 1);
                vqp[r] += __shfl_xor(vqp[r], 2);
                vqp[r] += __shfl_xor(vqp[r], 4);
                vqp[r] += __shfl_xor(vqp[r], 8);
            }
            if (l16 == 0) {
                f32x4 vq4 = {vqp[0], vqp[1], vqp[2], vqp[3]};
                *(f32x4*)(vq + cv0) = vq4;
            }
        }
        __syncthreads();   // BAR_B

        // ---- ph3: S^T, softmax, cs via vq, online factors, scaled-P store ----
        float a_scale;
        {
            const f32x4 z = {0.f, 0.f, 0.f, 0.f};
            float st[4][4];
            #pragma unroll
            for (int mt = 0; mt < 4; ++mt) {
                const int cA = mt * 16 + l16;
                const char* kr = (const char*)keysL + cA * 128;
                const int swc = (cA & 7) << 4;
                f32x4 s = MFMA16(*(const bf16x8*)(kr + ((quad * 16) ^ swc)), q0, z);
                s = MFMA16(*(const bf16x8*)(kr + ((quad * 16 + 64) ^ swc)), q1, s);
                bf16x4 k4 = *(const bf16x4*)((const char*)kcol64 + (mt * 16 + quad * 4) * 2);
                #pragma unroll
                for (int r = 0; r < 4; ++r)
                    st[mt][r] = fmaf(q64k, (float)k4[r], s[r]) * SCALE;
            }
            float m = st[0][0];
            #pragma unroll
            for (int mt = 0; mt < 4; ++mt)
                #pragma unroll
                for (int r = 0; r < 4; ++r) m = fmaxf(m, st[mt][r]);
            m = fmaxf(m, __shfl_xor(m, 16));
            m = fmaxf(m, __shfl_xor(m, 32));
            float sum = 0.f;
            #pragma unroll
            for (int mt = 0; mt < 4; ++mt)
                #pragma unroll
                for (int r = 0; r < 4; ++r) {
                    st[mt][r] = __expf(st[mt][r] - m);
                    sum += st[mt][r];
                }
            sum += __shfl_xor(sum, 16);
            sum += __shfl_xor(sum, 32);
            const float inv_k = __builtin_amdgcn_rcpf(sum);

            // d=64 output column + cs partial from fp32 P (shared shuffles)
            float o = 0.f, csp = 0.f;
            #pragma unroll
            for (int mt = 0; mt < 4; ++mt) {
                const int c0 = mt * 16 + quad * 4;
                bf16x4 v4 = *(const bf16x4*)((const char*)vcol64 + c0 * 2);
                const f32x4 vq4 = *(const f32x4*)(vq + c0);
                #pragma unroll
                for (int r = 0; r < 4; ++r) {
                    o   = fmaf(st[mt][r], (float)v4[r], o);
                    csp = fmaf(st[mt][r], vq4[r], csp);
                }
            }
            o += __shfl_xor(o, 16);
            o += __shfl_xor(o, 32);
            csp += __shfl_xor(csp, 16);
            csp += __shfl_xor(csp, 32);
            const float o64n = o * inv_k;
            const float cs = (csp * inv_k + cq64 * o64n) * SCALE;

            // online cross-softmax factors
            const float mn = fmaxf(mrun, cs);
            a_scale = __expf(mrun - mn);
            const float e = __expf(cs - mn);
            srun = srun * a_scale + e;
            O64  = O64 * a_scale + o64n * e;
            mrun = mn;
            const float ei = e * inv_k;

            // store P*ei into own k-row of xP (swizzled)
            const int swk = (krow & 7) << 4;
            char* prow = (char*)xP + krow * 128;
            #pragma unroll
            for (int mt = 0; mt < 4; ++mt) {
                bf16x4 p4;
                #pragma unroll
                for (int r = 0; r < 4; ++r) p4[r] = (__bf16)(st[mt][r] * ei);
                *(bf16x4*)(prow + (((mt * 16 + quad * 4) * 2) ^ swk)) = p4;
            }
        }
        // NO barrier: each wave reads back only the P rows it wrote.

        // ---- ph4: O = O*a + valsT@(P*ei) via MFMA C-operand accumulate ----
        {
            const int swk = (krow & 7) << 4;
            const char* prow = (const char*)xP + krow * 128;
            bf16x8 p0 = *(const bf16x8*)(prow + ((quad * 16) ^ swk));
            bf16x8 p1 = *(const bf16x8*)(prow + ((quad * 16 + 64) ^ swk));
            #pragma unroll
            for (int mt = 0; mt < 4; ++mt) {
                const int dA = mt * 16 + l16;
                const char* vr = (const char*)valsT + dA * 128;
                const int swd = (dA & 7) << 4;
                f32x4 c = O[mt];
                #pragma unroll
                for (int r = 0; r < 4; ++r) c[r] *= a_scale;
                c = MFMA16(*(const bf16x8*)(vr + ((quad * 16) ^ swd)), p0, c);
                c = MFMA16(*(const bf16x8*)(vr + ((quad * 16 + 64) ^ swd)), p1, c);
                O[mt] = c;
            }
        }
    }

    // ---- store partial: part[b][k][g][PST] = {O[0..64], m, s, pad} ----
    {
        float* dst = part + (((size_t)(b * 64 + krow)) * GRP + g) * PST;
        #pragma unroll
        for (int mt = 0; mt < 4; ++mt)
            *(f32x4*)(dst + mt * 16 + quad * 4) = O[mt];
        if (quad == 0) {
            f32x4 tail = {O64, mrun, srun, 0.f};
            *(f32x4*)(dst + 64) = tail;
        }
    }
}

// ---------------------------------------------------------------------------
// Kernel 4: merge GRP partials per (b,k): global softmax renorm, weighted
// sum, residual, LayerNorm.  grid (KQ, BATCH).
// ---------------------------------------------------------------------------
__global__ __launch_bounds__(256) void k_merge(
    const float* __restrict__ part, const float* __restrict__ rres,
    const float* __restrict__ gamma, const float* __restrict__ beta,
    float* __restrict__ out) {
    const int k = blockIdx.x;
    const int b = blockIdx.y;
    const int tid = threadIdx.x;

    __shared__ float pl[GRP * PST];
    __shared__ float fg[GRP];
    __shared__ float invS;
    __shared__ float vv[DDIM];
    __shared__ float stats[2];

    const float* src = part + ((size_t)(b * 64 + k)) * GRP * PST;
    for (int i = tid; i < GRP * PST; i += 256) pl[i] = src[i];
    __syncthreads();

    if (tid < GRP) {   // one wave: global max + renormalized sum
        const float m = pl[tid * PST + 65];
        float M = m;
        for (int off = 32; off; off >>= 1) M = fmaxf(M, __shfl_xor(M, off));
        const float f = __expf(m - M);
        float S = pl[tid * PST + 66] * f;
        for (int off = 32; off; off >>= 1) S += __shfl_xor(S, off);
        fg[tid] = f;
        if (tid == 0) invS = 1.0f / S;
    }
    __syncthreads();

    if (tid < DDIM) {
        float acc = 0.f;
        #pragma unroll 8
        for (int g = 0; g < GRP; ++g) acc = fmaf(pl[g * PST + tid], fg[g], acc);
        vv[tid] = acc * invS + rres[b * DDIM + tid];
    }
    __syncthreads();

    if (tid < 64) {
        float a  = vv[tid] + (tid == 0 ? vv[64] : 0.f);
        float sq = vv[tid] * vv[tid] + (tid == 0 ? vv[64] * vv[64] : 0.f);
        for (int off = 32; off; off >>= 1) {
            a  += __shfl_down(a, off);
            sq += __shfl_down(sq, off);
        }
        if (tid == 0) {
            const float mu  = a * (1.0f / DDIM);
            const float var = sq * (1.0f / DDIM) - mu * mu;
            stats[0] = mu;
            stats[1] = rsqrtf(var + 1e-5f);
        }
    }
    __syncthreads();
    if (tid < DDIM) {
        out[((size_t)(b * 64 + k)) * DDIM + tid] =
            (vv[tid] - stats[0]) * stats[1] * gamma[tid] + beta[tid];
    }
}

// ---------------------------------------------------------------------------
extern "C" void kernel_launch(void* const* d_in, const int* in_sizes, int n_in,
                              void* d_out, int out_size, void* d_ws, size_t ws_size,
                              hipStream_t stream) {
    const float* x    = (const float*)d_in[0];
    const float* Wq1  = (const float*)d_in[1];
    const float* bq1  = (const float*)d_in[2];
    const float* Wq2  = (const float*)d_in[3];
    const float* bq2  = (const float*)d_in[4];
    const float* Wk   = (const float*)d_in[5];
    const float* bk   = (const float*)d_in[6];
    const float* Wv   = (const float*)d_in[7];
    const float* bv   = (const float*)d_in[8];
    const float* cq   = (const float*)d_in[9];
    const float* pos  = (const float*)d_in[10];
    const float* Wr   = (const float*)d_in[11];
    const float* br   = (const float*)d_in[12];
    const float* gamma= (const float*)d_in[13];
    const float* beta = (const float*)d_in[14];
    float* out = (float*)d_out;

    // workspace layout (byte offsets, all 16B-aligned)
    char* w8 = (char*)d_ws;
    float*  partial = (float*)w8;                    // 532480 B @0
    float*  rres    = (float*)(w8 + 532480);         // 8320 B
    float*  q64     = (float*)(w8 + 540800);         // 8192 B
    float*  hbuf    = (float*)(w8 + 548992);         // 8320 B
    __bf16* qbf     = (__bf16*)(w8 + 557312);        // 262144 B
    __bf16* WkT     = (__bf16*)(w8 + 819456);        // 10240 B
    __bf16* WvT     = (__bf16*)(w8 + 829696);        // 10240 B
    float*  posK    = (float*)(w8 + 839936);         // 17408 B
    float*  posV    = (float*)(w8 + 857344);         // 17680 B
    float*  wkc     = (float*)(w8 + 875024);         // 272 B
    float*  wvc     = (float*)(w8 + 875296);         // 272 B
    float*  part    = (float*)(w8 + 875568);         // 41943040 B [b][k][g][80]

    k_prep<<<75, 256, 0, stream>>>(Wk, Wv, pos, WkT, WvT, posK, posV, wkc, wvc);
    k_gavg<<<dim3(64, BATCH), 256, 0, stream>>>(x, partial);
    k_qgen1<<<BATCH, 256, 0, stream>>>(partial, Wq1, bq1, Wr, br, hbuf, rres);
    k_qgen2<<<dim3(17, BATCH), 256, 0, stream>>>(hbuf, Wq2, bq2, qbf, q64);
    k_attn<<<dim3(GRP, BATCH), 256, 0, stream>>>(x, qbf, q64, WkT, WvT,
                                                 posK, posV, wkc, wvc,
                                                 bk, bv, cq, part);
    k_merge<<<dim3(KQ, BATCH), 256, 0, stream>>>(part, rres, gamma, beta, out);
}